// Round 5
// baseline (62.960 us; speedup 1.0000x reference)
//
#include <hip/hip_runtime.h>
#include <hip/hip_bf16.h>

// SingleDimHistLayer: soft histogram via fine-grid deposit + 145-tap convolution.
//
// Math: out[b,k] = (1/N) * sum_n [ g(u_n - k) - g(u_n - k - 1) ],  g(v)=sigmoid(2.5 v),
//       u = x*256.  Terms negligible outside |u - k - 0.5| <= 4.5 -> 145 fine taps
//       at 1/16 resolution.
// Deposit: nearest fine node (midpoint rule), 1 ds_add_u32 per sample.
//          MEASURED (R2->R4): int LDS atomics are bank-parallel (~9 us device-wide
//          savings vs f32); float LDS atomics lane-serialize (~3 cyc/lane). Use ints.
// Conv:   256 threads x 145 taps, int->float at read; 1/N folded into weights.
// Grid:   512 (2 blocks/CU) so one block's conv overlaps the other's deposit/load.

constexpr int KBINS   = 256;
constexpr int FSUB    = 16;                  // fine nodes per bin
constexpr int LPAD    = 64;                  // left halo (k=0 window reaches f=-64)
constexpr int TAPS    = 145;                 // window f in [16k-64, 16k+80]
// bank-skew addressing: addr = p + (p>>5); max logical p = 4224 -> 4356
constexpr int LDS_FH  = 4360;
constexpr int NPB     = 512 * 512;           // samples per batch
constexpr int BLK_PER_BATCH = 64;            // 4096 samples per block, grid = 512
constexpr int CHUNK   = NPB / BLK_PER_BATCH; // 4096

__device__ __forceinline__ int skew(int p) { return p + (p >> 5); }

__global__ __launch_bounds__(256)
void hist_kernel(const float* __restrict__ x, float* __restrict__ out) {
    __shared__ unsigned fh[LDS_FH];
    __shared__ float w[TAPS];
    const int tid = threadIdx.x;

    // zero fine hist
    #pragma unroll
    for (int i = tid; i < LDS_FH; i += 256) fh[i] = 0u;

    // conv weights (1/N folded in):
    // w[j] = [sigmoid(0.15625*(j-64)) - sigmoid(0.15625*(j-80))] / N
    if (tid < TAPS) {
        float a = 0.15625f * (float)(tid - 64);
        float b = 0.15625f * (float)(tid - 80);
        w[tid] = (1.f / (1.f + __expf(-a)) - 1.f / (1.f + __expf(-b)))
                 * (1.f / (float)NPB);
    }
    __syncthreads();

    const int b     = blockIdx.x / BLK_PER_BATCH;
    const int chunk = blockIdx.x % BLK_PER_BATCH;
    const float4* xv = (const float4*)(x + (size_t)b * NPB + (size_t)chunk * CHUNK);

    // deposit: 4096 samples/block, 4 float4 per thread, 1 int LDS atomic per sample
    #pragma unroll
    for (int it = 0; it < CHUNK / (4 * 256); ++it) {
        float4 v = xv[it * 256 + tid];
        float vals[4] = {v.x, v.y, v.z, v.w};
        int addr[4];
        #pragma unroll
        for (int c = 0; c < 4; ++c) {
            float s = vals[c] * (float)(KBINS * FSUB);   // position on fine grid
            s = fminf(fmaxf(s, 0.f), 4096.f);            // defensive clamp
            addr[c] = skew((int)(s + 0.5f) + LPAD);      // nearest node (s >= 0)
        }
        #pragma unroll
        for (int c = 0; c < 4; ++c)
            atomicAdd(&fh[addr[c]], 1u);
    }
    __syncthreads();

    // convolve: thread k computes coarse bin k from taps [16k, 16k+144] (padded idx)
    {
        float acc = 0.f;
        const int base = tid * FSUB;
        #pragma unroll 8
        for (int j = 0; j < TAPS; ++j)
            acc += w[j] * (float)fh[skew(base + j)];
        unsafeAtomicAdd(&out[b * KBINS + tid], acc);
    }
}

extern "C" void kernel_launch(void* const* d_in, const int* in_sizes, int n_in,
                              void* d_out, int out_size, void* d_ws, size_t ws_size,
                              hipStream_t stream) {
    const float* x = (const float*)d_in[0];
    float* out = (float*)d_out;
    const int B = in_sizes[0] / NPB;   // 8

    hipMemsetAsync(d_out, 0, (size_t)out_size * sizeof(float), stream);
    hist_kernel<<<B * BLK_PER_BATCH, 256, 0, stream>>>(x, out);
}